// Round 1
// baseline (88.919 us; speedup 1.0000x reference)
//
#include <hip/hip_runtime.h>

// Problem constants
//  B=256 batches, N=512 cells, G=117 genes, CH=25 conv channels
//  flat feature = 625, padded per-channel to 32 -> K = 25*32 = 800
//  G padded to 128 (8 col-fragments of 16)

typedef __attribute__((ext_vector_type(4))) float f32x4;
typedef __attribute__((ext_vector_type(8))) short short8;

// workspace layout (needs ~1.2 MB)
#define WB_BYTES   204800      // 25*8*64*8 bf16 fragment-linear W_reg
#define GLOB_OFF   204800      // 256 floats
#define SPOT_OFF   208896      // [256][8][128] f32 partials = 1,048,576 B

#define SPOT_OUT_OFF 0
#define CELL_OUT_OFF 29952
#define OUT1_OUT_OFF 15365376

__device__ __forceinline__ unsigned short f2bf(float x) {
  unsigned int u = __builtin_bit_cast(unsigned int, x);
  u = (u + 0x7FFFu + ((u >> 16) & 1u)) >> 16;   // RNE
  return (unsigned short)u;
}

// blocks 0..255: glob[b] = ELU(patch_embed(spot_images[b]) . W_glob + b_glob)
// blocks 256..455: convert W_reg -> bf16 MFMA-B-fragment-linear layout
__global__ __launch_bounds__(128) void prep_kernel(
    const float* __restrict__ spot_images, const float* __restrict__ W_patch,
    const float* __restrict__ b_patch, const float* __restrict__ W_glob,
    const float* __restrict__ b_glob, const float* __restrict__ W_reg,
    unsigned short* __restrict__ wb, float* __restrict__ glob) {
  int bid = blockIdx.x;
  int tid = threadIdx.x;
  if (bid < 256) {
    __shared__ float red[75];
    if (tid < 75) {
      int token = tid / 3;
      int chan = tid - token * 3;
      int ty = token / 5, tx = token - ty * 5;
      const float* img = spot_images + bid * 784 + (ty * 5) * 28 + tx * 5;
      float a = 0.f;
      #pragma unroll
      for (int i = 0; i < 5; ++i)
        #pragma unroll
        for (int j = 0; j < 5; ++j)
          a = fmaf(img[i * 28 + j], W_patch[chan * 25 + i * 5 + j], a);
      a += b_patch[chan];
      red[tid] = a * W_glob[tid];
    }
    __syncthreads();
    if (tid == 0) {
      float s = b_glob[0];
      for (int k = 0; k < 75; ++k) s += red[k];
      glob[bid] = (s > 0.f) ? s : expm1f(s);
    }
  } else {
    int idx = bid - 256;               // 0..199 = (ch, f)
    int ch = idx >> 3, f = idx & 7;
    if (tid < 64) {
      int l = tid;
      int g = f * 16 + (l & 15);
      int pbase = (l >> 4) * 8;        // k-within-ch = pbase + i
      unsigned int u[4];
      #pragma unroll
      for (int k = 0; k < 4; ++k) {
        unsigned short lo = 0, hi = 0;
        int p0 = pbase + 2 * k, p1 = p0 + 1;
        if (g < 117 && p0 < 25) lo = f2bf(W_reg[g * 625 + ch * 25 + p0]);
        if (g < 117 && p1 < 25) hi = f2bf(W_reg[g * 625 + ch * 25 + p1]);
        u[k] = (unsigned int)lo | ((unsigned int)hi << 16);
      }
      uint4* dst = (uint4*)(wb + (((ch * 8 + f) * 64) + l) * 8);
      *dst = make_uint4(u[0], u[1], u[2], u[3]);
    }
  }
}

// One block = one (batch b, 64-cell tile). 512 threads = 8 waves.
// Phase 1: stage raw 7x7 images to LDS. Phase 2: conv -> bf16 A-tile in LDS
// (layout [ch][cell][32], 4-slot rotation swizzle on 16B chunks).
// Phase 3: wave w computes cells 0..63 x genes 16w..16w+15 via 25 kt * 4 MFMA.
// Epilogue: +b_reg +glob, ReLU, store cell & out1, spot partials to ws.
__global__ __launch_bounds__(512, 2) void main_kernel(
    const float* __restrict__ images, const float* __restrict__ W_emph,
    const float* __restrict__ b_emph, const float* __restrict__ b_reg,
    const unsigned short* __restrict__ wb, const float* __restrict__ glob,
    float* __restrict__ out, float* __restrict__ spotp) {
  __shared__ unsigned short A_u16[25 * 64 * 32];   // 102400 B
  __shared__ float img_lds[64 * 49];               // 12544 B
  int tid = threadIdx.x;
  int bid = blockIdx.x;
  int b = bid >> 3, tile = bid & 7;
  int n0 = tile * 64;

  // ---- stage images (12544 B contiguous, 784 float4) ----
  const float4* gsrc = (const float4*)(images + (size_t)(b * 512 + n0) * 49);
  float4* ldst = (float4*)img_lds;
  ldst[tid] = gsrc[tid];
  if (tid < 272) ldst[tid + 512] = gsrc[tid + 512];
  __syncthreads();

  // ---- conv: thread = (cell = tid&63, ch-group = wave) ----
  {
    int cell = tid & 63;
    int grp = __builtin_amdgcn_readfirstlane(tid >> 6);  // wave-uniform
    float img[49];
    #pragma unroll
    for (int i = 0; i < 49; ++i) img[i] = img_lds[cell * 49 + i];
    int sw = (cell >> 1) & 3;
    for (int ch = grp; ch < 25; ch += 8) {
      float wg[9];
      #pragma unroll
      for (int k = 0; k < 9; ++k) wg[k] = W_emph[ch * 9 + k];   // scalar loads
      float bias = b_emph[ch];
      unsigned short h[25];
      #pragma unroll
      for (int p = 0; p < 25; ++p) {
        int oy = p / 5, ox = p % 5;
        float a = bias;
        #pragma unroll
        for (int ky = 0; ky < 3; ++ky)
          #pragma unroll
          for (int kx = 0; kx < 3; ++kx)
            a = fmaf(img[(oy + ky) * 7 + (ox + kx)], wg[ky * 3 + kx], a);
        h[p] = f2bf(fmaxf(a, 0.f));
      }
      unsigned int u[16];
      #pragma unroll
      for (int k = 0; k < 12; ++k)
        u[k] = (unsigned int)h[2 * k] | ((unsigned int)h[2 * k + 1] << 16);
      u[12] = (unsigned int)h[24];
      u[13] = 0; u[14] = 0; u[15] = 0;
      uint4* dst = (uint4*)(A_u16 + (ch * 64 + cell) * 32);
      #pragma unroll
      for (int i = 0; i < 4; ++i)
        dst[(i + sw) & 3] = make_uint4(u[4 * i], u[4 * i + 1], u[4 * i + 2], u[4 * i + 3]);
    }
  }
  __syncthreads();

  // ---- MFMA: wave w owns col-frag w (g = 16w..16w+15), rows 0..63 ----
  int l = tid & 63;
  int w = tid >> 6;
  int m = l & 15;
  int kgrp = l >> 4;
  int slot = (kgrp + (m >> 1)) & 3;         // rotation swizzle (r-independent)
  const short8* A8 = (const short8*)A_u16;  // [ch*256 + cell*4 + slot]
  const short8* B8 = (const short8*)wb;     // [(ch*8+f)*64 + lane]
  f32x4 acc0 = {0.f, 0.f, 0.f, 0.f};
  f32x4 acc1 = acc0, acc2 = acc0, acc3 = acc0;
  for (int ch = 0; ch < 25; ++ch) {
    short8 bf = B8[(ch * 8 + w) * 64 + l];
    short8 a0 = A8[ch * 256 + (0 * 16 + m) * 4 + slot];
    short8 a1 = A8[ch * 256 + (1 * 16 + m) * 4 + slot];
    short8 a2 = A8[ch * 256 + (2 * 16 + m) * 4 + slot];
    short8 a3 = A8[ch * 256 + (3 * 16 + m) * 4 + slot];
    acc0 = __builtin_amdgcn_mfma_f32_16x16x32_bf16(a0, bf, acc0, 0, 0, 0);
    acc1 = __builtin_amdgcn_mfma_f32_16x16x32_bf16(a1, bf, acc1, 0, 0, 0);
    acc2 = __builtin_amdgcn_mfma_f32_16x16x32_bf16(a2, bf, acc2, 0, 0, 0);
    acc3 = __builtin_amdgcn_mfma_f32_16x16x32_bf16(a3, bf, acc3, 0, 0, 0);
  }

  // ---- epilogue ----
  float gb = glob[b];
  int g = w * 16 + m;
  bool gok = g < 117;
  float br = gok ? b_reg[g] : 0.f;
  size_t rowbase = (size_t)(b * 512 + n0);
  float* cellout = out + CELL_OUT_OFF + rowbase * 117;
  float* o1out = out + OUT1_OUT_OFF + rowbase * 117;
  float spotacc = 0.f;
  auto epi = [&](int R, f32x4 A) {
    #pragma unroll
    for (int jj = 0; jj < 4; ++jj) {
      int n = R * 16 + kgrp * 4 + jj;       // C/D: row = (l>>4)*4 + reg
      float v = fmaxf(A[jj] + br + gb, 0.f);
      spotacc += v;
      if (gok) {
        cellout[n * 117 + g] = v;
        o1out[n * 117 + g] = gb;
      }
    }
  };
  epi(0, acc0); epi(1, acc1); epi(2, acc2); epi(3, acc3);

  float v = spotacc;
  v += __shfl_xor(v, 16, 64);
  v += __shfl_xor(v, 32, 64);
  if (l < 16) spotp[(size_t)(b * 8 + tile) * 128 + w * 16 + l] = v;
}

// spot[b][g] = sum of 8 tile partials
__global__ __launch_bounds__(256) void spot_reduce(
    const float* __restrict__ spotp, float* __restrict__ out) {
  int idx = blockIdx.x * 256 + threadIdx.x;   // exactly 117*256 = 29952
  int b = idx / 117;
  int g = idx - b * 117;
  float s = 0.f;
  #pragma unroll
  for (int t = 0; t < 8; ++t) s += spotp[(size_t)(b * 8 + t) * 128 + g];
  out[SPOT_OUT_OFF + idx] = s;
}

extern "C" void kernel_launch(void* const* d_in, const int* in_sizes, int n_in,
                              void* d_out, int out_size, void* d_ws, size_t ws_size,
                              hipStream_t stream) {
  const float* images      = (const float*)d_in[0];
  const float* spot_images = (const float*)d_in[1];
  // d_in[2] = gene_expression (unused by the reference)
  const float* W_emph = (const float*)d_in[3];
  const float* b_emph = (const float*)d_in[4];
  const float* W_reg  = (const float*)d_in[5];
  const float* b_reg  = (const float*)d_in[6];
  const float* W_patch = (const float*)d_in[7];
  const float* b_patch = (const float*)d_in[8];
  const float* W_glob  = (const float*)d_in[9];
  const float* b_glob  = (const float*)d_in[10];
  float* out = (float*)d_out;

  unsigned short* wb = (unsigned short*)d_ws;
  float* glob  = (float*)((char*)d_ws + GLOB_OFF);
  float* spotp = (float*)((char*)d_ws + SPOT_OFF);

  prep_kernel<<<456, 128, 0, stream>>>(spot_images, W_patch, b_patch, W_glob,
                                       b_glob, W_reg, wb, glob);
  main_kernel<<<2048, 512, 0, stream>>>(images, W_emph, b_emph, b_reg, wb, glob,
                                        out, spotp);
  spot_reduce<<<117, 256, 0, stream>>>(spotp, out);
}

// Round 2
// 76.366 us; speedup vs baseline: 1.1644x; 1.1644x over previous
//
#include <hip/hip_runtime.h>

// B=256 batches, N=512 cells, G=117 genes, CH=25 conv channels
// feature = 625 padded per-channel to 32 -> K = 800; G padded to 128.
// Main kernel: block = 64 cells x 128 genes, 8 waves (2 row x 4 col),
// wave tile 32x32 via mfma_f32_32x32x16_bf16, channels in 2 passes
// (13+12) through one 53 KB LDS A-buffer -> 2 blocks/CU.

typedef __attribute__((ext_vector_type(4))) float f32x4;
typedef __attribute__((ext_vector_type(16))) float f32x16;
typedef __attribute__((ext_vector_type(8))) short short8;

#define GLOB_OFF   204800      // wb = 204800 B, then 256 floats glob
#define SPOT_OFF   208896      // [256][8][128] f32 partials = 1 MB

#define SPOT_OUT_OFF 0
#define CELL_OUT_OFF 29952
#define OUT1_OUT_OFF 15365376

__device__ __forceinline__ unsigned short f2bf(float x) {
  unsigned int u = __builtin_bit_cast(unsigned int, x);
  u = (u + 0x7FFFu + ((u >> 16) & 1u)) >> 16;   // RNE
  return (unsigned short)u;
}

// blocks 0..255: glob[b] = ELU(patch_embed(spot_images[b]) . W_glob + b_glob)
// blocks 256..455: W_reg -> bf16 B-fragment layout for 32x32x16 MFMA:
//   wb[((ch*8 + wc*2 + h)*64 + lane)*8 shorts]
//   lane: col g = wc*32 + (lane&31); k-in-ch p = h*16 + (lane>>5)*8 + j
__global__ __launch_bounds__(128) void prep_kernel(
    const float* __restrict__ spot_images, const float* __restrict__ W_patch,
    const float* __restrict__ b_patch, const float* __restrict__ W_glob,
    const float* __restrict__ b_glob, const float* __restrict__ W_reg,
    unsigned short* __restrict__ wb, float* __restrict__ glob) {
  int bid = blockIdx.x;
  int tid = threadIdx.x;
  if (bid < 256) {
    __shared__ float red[75];
    if (tid < 75) {
      int token = tid / 3;
      int chan = tid - token * 3;
      int ty = token / 5, tx = token - ty * 5;
      const float* img = spot_images + bid * 784 + (ty * 5) * 28 + tx * 5;
      float a = 0.f;
      #pragma unroll
      for (int i = 0; i < 5; ++i)
        #pragma unroll
        for (int j = 0; j < 5; ++j)
          a = fmaf(img[i * 28 + j], W_patch[chan * 25 + i * 5 + j], a);
      a += b_patch[chan];
      red[tid] = a * W_glob[tid];
    }
    __syncthreads();
    if (tid == 0) {
      float s = b_glob[0];
      for (int k = 0; k < 75; ++k) s += red[k];
      glob[bid] = (s > 0.f) ? s : expm1f(s);
    }
  } else {
    int idx = bid - 256;               // 0..199 = (ch, wc, h)
    int ch = idx >> 3;
    int wc = (idx >> 1) & 3;
    int h = idx & 1;
    if (tid < 64) {
      int lg = tid & 31;
      int kh = tid >> 5;
      int g = wc * 32 + lg;
      unsigned int u[4];
      #pragma unroll
      for (int k = 0; k < 4; ++k) {
        int p0 = h * 16 + kh * 8 + 2 * k, p1 = p0 + 1;
        unsigned short lo = 0, hi = 0;
        if (g < 117 && p0 < 25) lo = f2bf(W_reg[g * 625 + ch * 25 + p0]);
        if (g < 117 && p1 < 25) hi = f2bf(W_reg[g * 625 + ch * 25 + p1]);
        u[k] = (unsigned int)lo | ((unsigned int)hi << 16);
      }
      uint4* dst = (uint4*)(wb + (((ch * 8 + wc * 2 + h) * 64) + tid) * 8);
      *dst = make_uint4(u[0], u[1], u[2], u[3]);
    }
  }
}

// One block = (batch b, 64-cell tile). 512 threads = 8 waves (wr 0..1, wc 0..3).
__global__ __launch_bounds__(512, 4) void main_kernel(
    const float* __restrict__ images, const float* __restrict__ W_emph,
    const float* __restrict__ b_emph, const float* __restrict__ b_reg,
    const unsigned short* __restrict__ wb, const float* __restrict__ glob,
    float* __restrict__ out, float* __restrict__ spotp) {
  __shared__ unsigned short A_u16[13 * 64 * 32];   // 53248 B
  __shared__ float img_lds[64 * 49];               // 12544 B
  __shared__ float red[2][128];                    // 1024 B
  int tid = threadIdx.x;
  int bid = blockIdx.x;
  int b = bid >> 3, tile = bid & 7;
  int n0 = tile * 64;

  // ---- stage images (784 float4) ----
  const float4* gsrc = (const float4*)(images + (size_t)(b * 512 + n0) * 49);
  float4* ldst = (float4*)img_lds;
  ldst[tid] = gsrc[tid];
  if (tid < 272) ldst[tid + 512] = gsrc[tid + 512];
  __syncthreads();

  int l = tid & 63;
  int wu = __builtin_amdgcn_readfirstlane(tid >> 6);  // wave id 0..7
  int wr = wu >> 2, wc = wu & 3;
  int cell = l;                 // conv role
  int r = wr * 32 + (l & 31);   // A-row this lane reads
  int cA = l >> 5;
  const short8* A8 = (const short8*)A_u16;
  const short8* B8 = (const short8*)wb;
  f32x16 acc;
  #pragma unroll
  for (int i = 0; i < 16; ++i) acc[i] = 0.f;

  // conv pass: channels [c0, c0+np), wave wu handles ch = c0+wu, c0+wu+8
  auto conv_pass = [&](int c0, int np) {
    float img[49];
    #pragma unroll
    for (int i = 0; i < 49; ++i) img[i] = img_lds[cell * 49 + i];
    for (int ch = c0 + wu; ch < c0 + np; ch += 8) {
      int ci = ch - c0;
      float wg[9];
      #pragma unroll
      for (int k = 0; k < 9; ++k) wg[k] = W_emph[ch * 9 + k];
      float bias = b_emph[ch];
      unsigned short h[25];
      #pragma unroll
      for (int p = 0; p < 25; ++p) {
        int oy = p / 5, ox = p % 5;
        float a = bias;
        #pragma unroll
        for (int ky = 0; ky < 3; ++ky)
          #pragma unroll
          for (int kx = 0; kx < 3; ++kx)
            a = fmaf(img[(oy + ky) * 7 + (ox + kx)], wg[ky * 3 + kx], a);
        h[p] = f2bf(fmaxf(a, 0.f));
      }
      unsigned int u[16];
      #pragma unroll
      for (int k = 0; k < 12; ++k)
        u[k] = (unsigned int)h[2 * k] | ((unsigned int)h[2 * k + 1] << 16);
      u[12] = (unsigned int)h[24];
      u[13] = 0; u[14] = 0; u[15] = 0;
      uint4* dst = (uint4*)(A_u16 + (ci * 64 + cell) * 32);
      #pragma unroll
      for (int cc = 0; cc < 4; ++cc)
        dst[(cc + cell) & 3] =
            make_uint4(u[4 * cc], u[4 * cc + 1], u[4 * cc + 2], u[4 * cc + 3]);
    }
  };

  // mfma pass: A chunk c holds k 8c..8c+7 of the channel; slot=(c+row)&3
  auto mfma_pass = [&](int c0, int np) {
    for (int ci = 0; ci < np; ++ci) {
      int ch = c0 + ci;
      short8 b0 = B8[(ch * 8 + wc * 2 + 0) * 64 + l];
      short8 b1 = B8[(ch * 8 + wc * 2 + 1) * 64 + l];
      short8 a0 = A8[(ci * 64 + r) * 4 + ((cA + r) & 3)];
      short8 a1 = A8[(ci * 64 + r) * 4 + ((cA + 2 + r) & 3)];
      acc = __builtin_amdgcn_mfma_f32_32x32x16_bf16(a0, b0, acc, 0, 0, 0);
      acc = __builtin_amdgcn_mfma_f32_32x32x16_bf16(a1, b1, acc, 0, 0, 0);
    }
  };

  conv_pass(0, 13);
  __syncthreads();
  mfma_pass(0, 13);
  __syncthreads();          // all A reads done before overwrite
  conv_pass(13, 12);
  __syncthreads();
  mfma_pass(13, 12);

  // ---- epilogue: C/D 32x32 layout col=lane&31, row=(reg&3)+8*(reg>>2)+4*(lane>>5)
  float gb = glob[b];
  int g = wc * 32 + (l & 31);
  bool gok = g < 117;
  float br = gok ? b_reg[g] : 0.f;
  size_t rowbase = (size_t)(b * 512 + n0);
  float* cellout = out + CELL_OUT_OFF + rowbase * 117;
  float* o1out = out + OUT1_OUT_OFF + rowbase * 117;
  float spotacc = 0.f;
  #pragma unroll
  for (int reg = 0; reg < 16; ++reg) {
    int n = wr * 32 + (reg & 3) + 8 * (reg >> 2) + 4 * (l >> 5);
    float v = fmaxf(acc[reg] + br + gb, 0.f);
    spotacc += v;
    if (gok) {
      cellout[(size_t)n * 117 + g] = v;
      o1out[(size_t)n * 117 + g] = gb;
    }
  }
  float v2 = spotacc + __shfl_xor(spotacc, 32, 64);
  if ((l & 32) == 0) red[wr][wc * 32 + (l & 31)] = v2;
  __syncthreads();
  if (tid < 128)
    spotp[(size_t)(b * 8 + tile) * 128 + tid] = red[0][tid] + red[1][tid];
}

// spot[b][g] = sum of 8 tile partials
__global__ __launch_bounds__(256) void spot_reduce(
    const float* __restrict__ spotp, float* __restrict__ out) {
  int idx = blockIdx.x * 256 + threadIdx.x;   // exactly 117*256 = 29952
  int b = idx / 117;
  int g = idx - b * 117;
  float s = 0.f;
  #pragma unroll
  for (int t = 0; t < 8; ++t) s += spotp[(size_t)(b * 8 + t) * 128 + g];
  out[SPOT_OUT_OFF + idx] = s;
}

extern "C" void kernel_launch(void* const* d_in, const int* in_sizes, int n_in,
                              void* d_out, int out_size, void* d_ws, size_t ws_size,
                              hipStream_t stream) {
  const float* images      = (const float*)d_in[0];
  const float* spot_images = (const float*)d_in[1];
  // d_in[2] = gene_expression (unused by the reference)
  const float* W_emph = (const float*)d_in[3];
  const float* b_emph = (const float*)d_in[4];
  const float* W_reg  = (const float*)d_in[5];
  const float* b_reg  = (const float*)d_in[6];
  const float* W_patch = (const float*)d_in[7];
  const float* b_patch = (const float*)d_in[8];
  const float* W_glob  = (const float*)d_in[9];
  const float* b_glob  = (const float*)d_in[10];
  float* out = (float*)d_out;

  unsigned short* wb = (unsigned short*)d_ws;
  float* glob  = (float*)((char*)d_ws + GLOB_OFF);
  float* spotp = (float*)((char*)d_ws + SPOT_OFF);

  prep_kernel<<<456, 128, 0, stream>>>(spot_images, W_patch, b_patch, W_glob,
                                       b_glob, W_reg, wb, glob);
  main_kernel<<<2048, 512, 0, stream>>>(images, W_emph, b_emph, b_reg, wb, glob,
                                        out, spotp);
  spot_reduce<<<117, 256, 0, stream>>>(spotp, out);
}

// Round 3
// 64.641 us; speedup vs baseline: 1.3756x; 1.1814x over previous
//
#include <hip/hip_runtime.h>

// B=256, N=512 cells, G=117 genes, CH=25 conv channels.
// Conv reframed as MFMA: O1^T(640x64cells) = W_big^T(640x64i) @ img(64i x 64cells)
//   j = ch*25+p (625 real, pad 640), i = 7x7 pixel (49 real; i=49 -> ones column
//   carrying b_emph; pad 64). ReLU+bf16 -> A2 (chunk-major LDS, 2 halves of 320).
// mm2: out(64cells x 128genes) += A2 @ W_reg^T, K=640, 8 waves (2x4) of 32x32 tiles.

typedef __attribute__((ext_vector_type(16))) float f32x16;
typedef __attribute__((ext_vector_type(8))) short short8;

#define WB_OFF    0          // 163840 B : W_reg bf16 B-frags [40 ksteps][4 wc][64][8]
#define WBIG_OFF  163840     // 81920 B  : W_big^T bf16 A-frags [20 jt][4 s][64][8]
#define GLOB_OFF  245760     // 1024 B   : glob[256]
#define SPOT_OFF  246784     // 1 MB     : [256][8][128] f32 partials

#define SPOT_OUT_OFF 0
#define CELL_OUT_OFF 29952
#define OUT1_OUT_OFF 15365376

__device__ __forceinline__ unsigned short f2bf(float x) {
  unsigned int u = __builtin_bit_cast(unsigned int, x);
  u = (u + 0x7FFFu + ((u >> 16) & 1u)) >> 16;   // RNE
  return (unsigned short)u;
}

// blocks 0..255: glob ; 256..335: wbig (jt 0..19 x s 0..3) ; 336..495: wb (sg 0..39 x wc 0..3)
__global__ __launch_bounds__(128) void prep_kernel(
    const float* __restrict__ spot_images, const float* __restrict__ W_patch,
    const float* __restrict__ b_patch, const float* __restrict__ W_glob,
    const float* __restrict__ b_glob, const float* __restrict__ W_reg,
    const float* __restrict__ W_emph, const float* __restrict__ b_emph,
    unsigned short* __restrict__ wb, unsigned short* __restrict__ wbig,
    float* __restrict__ glob) {
  int bid = blockIdx.x;
  int tid = threadIdx.x;
  if (bid < 256) {
    __shared__ float red[75];
    if (tid < 75) {
      int token = tid / 3;
      int chan = tid - token * 3;
      int ty = token / 5, tx = token - ty * 5;
      const float* img = spot_images + bid * 784 + (ty * 5) * 28 + tx * 5;
      float a = 0.f;
      #pragma unroll
      for (int i = 0; i < 5; ++i)
        #pragma unroll
        for (int j = 0; j < 5; ++j)
          a = fmaf(img[i * 28 + j], W_patch[chan * 25 + i * 5 + j], a);
      a += b_patch[chan];
      red[tid] = a * W_glob[tid];
    }
    __syncthreads();
    if (tid == 0) {
      float s = b_glob[0];
      for (int k = 0; k < 75; ++k) s += red[k];
      glob[bid] = (s > 0.f) ? s : expm1f(s);
    }
  } else if (bid < 336) {
    int idx = bid - 256;               // jt*4 + s
    int jt = idx >> 2, s = idx & 3;
    if (tid < 64) {
      int j = jt * 32 + (tid & 31);
      int h = tid >> 5;
      unsigned short hv[8];
      #pragma unroll
      for (int jj = 0; jj < 8; ++jj) {
        int i = s * 16 + h * 8 + jj;
        float val = 0.f;
        if (j < 625) {
          int ch = j / 25, p = j % 25;
          int oy = p / 5, ox = p - oy * 5;
          if (i < 49) {
            int iy = i / 7, ix = i - iy * 7;
            int ky = iy - oy, kx = ix - ox;
            if (ky >= 0 && ky < 3 && kx >= 0 && kx < 3)
              val = W_emph[ch * 9 + ky * 3 + kx];
          } else if (i == 49) {
            val = b_emph[ch];
          }
        }
        hv[jj] = f2bf(val);
      }
      unsigned int u[4];
      #pragma unroll
      for (int k = 0; k < 4; ++k)
        u[k] = (unsigned int)hv[2 * k] | ((unsigned int)hv[2 * k + 1] << 16);
      ((uint4*)wbig)[idx * 64 + tid] = make_uint4(u[0], u[1], u[2], u[3]);
    }
  } else {
    int idx = bid - 336;               // sg*4 + wc
    int sg = idx >> 2, wcp = idx & 3;
    if (tid < 64) {
      int g = wcp * 32 + (tid & 31);
      int h = tid >> 5;
      unsigned short hv[8];
      #pragma unroll
      for (int jj = 0; jj < 8; ++jj) {
        int k = sg * 16 + h * 8 + jj;
        float val = (g < 117 && k < 625) ? W_reg[g * 625 + k] : 0.f;
        hv[jj] = f2bf(val);
      }
      unsigned int u[4];
      #pragma unroll
      for (int k = 0; k < 4; ++k)
        u[k] = (unsigned int)hv[2 * k] | ((unsigned int)hv[2 * k + 1] << 16);
      ((uint4*)wb)[idx * 64 + tid] = make_uint4(u[0], u[1], u[2], u[3]);
    }
  }
}

// One block = (batch b, 64-cell tile). 512 threads = 8 waves (wr 0..1 x wc 0..3).
__global__ __launch_bounds__(512, 4) void main_kernel(
    const float* __restrict__ images, const float* __restrict__ b_reg,
    const unsigned short* __restrict__ wb, const unsigned short* __restrict__ wbig,
    const float* __restrict__ glob, float* __restrict__ out,
    float* __restrict__ spotp) {
  __shared__ unsigned short A2s[40 * 64 * 8];    // 40960 B, [jc][cell][8 shorts]
  __shared__ unsigned short imgbs[8 * 64 * 8];   // 8192 B,  [kc][cell][8 shorts]
  __shared__ float red[2][128];                  // 1024 B
  int tid = threadIdx.x;
  int bid = blockIdx.x;
  int b = bid >> 3, tile = bid & 7;
  int n0 = tile * 64;

  // ---- stage img -> bf16 chunk-major LDS (i=49 -> 1.0 bias column) ----
  {
    int cell = tid & 63, kc = tid >> 6;
    const float* src = images + (size_t)(b * 512 + n0 + cell) * 49 + kc * 8;
    float v[8];
    #pragma unroll
    for (int j = 0; j < 8; ++j) v[j] = 0.f;
    if (kc < 6) {
      #pragma unroll
      for (int j = 0; j < 8; ++j) v[j] = src[j];
    } else if (kc == 6) {
      v[0] = src[0];
      v[1] = 1.0f;
    }
    unsigned int u[4];
    #pragma unroll
    for (int k = 0; k < 4; ++k)
      u[k] = (unsigned int)f2bf(v[2 * k]) | ((unsigned int)f2bf(v[2 * k + 1]) << 16);
    ((uint4*)imgbs)[kc * 64 + cell] = make_uint4(u[0], u[1], u[2], u[3]);
  }
  __syncthreads();

  int l = tid & 63;
  int wu = __builtin_amdgcn_readfirstlane(tid >> 6);
  int wr = wu >> 2, wc = wu & 3, ctw = wu & 1;
  int m = l & 31, hh = l >> 5;
  int cellw = ctw * 32 + m;
  const short8* imgb8 = (const short8*)imgbs;
  const short8* A2r = (const short8*)A2s;
  const short8* wb8 = (const short8*)wb;
  const short8* wbig8 = (const short8*)wbig;

  f32x16 acc;
  #pragma unroll
  for (int i = 0; i < 16; ++i) acc[i] = 0.f;

  for (int hf = 0; hf < 2; ++hf) {
    // ---- mm1: conv via MFMA, tiles T = wu, wu+8, wu+16 (ct = wu&1 fixed) ----
    #pragma unroll
    for (int t = 0; t < 3; ++t) {
      int T = wu + 8 * t;
      if (T < 20) {
        int jt = T >> 1;
        f32x16 o;
        #pragma unroll
        for (int i = 0; i < 16; ++i) o[i] = 0.f;
        #pragma unroll
        for (int s = 0; s < 4; ++s) {
          short8 a = wbig8[((hf * 10 + jt) * 4 + s) * 64 + l];
          short8 bf = imgb8[(2 * s + hh) * 64 + cellw];
          o = __builtin_amdgcn_mfma_f32_32x32x16_bf16(a, bf, o, 0, 0, 0);
        }
        // relu + pack: reg quad q holds j = jt*32 + 8q + 4*hh + {0..3} for col cellw
        #pragma unroll
        for (int q = 0; q < 4; ++q) {
          unsigned int u0 = (unsigned int)f2bf(fmaxf(o[4 * q + 0], 0.f)) |
                            ((unsigned int)f2bf(fmaxf(o[4 * q + 1], 0.f)) << 16);
          unsigned int u1 = (unsigned int)f2bf(fmaxf(o[4 * q + 2], 0.f)) |
                            ((unsigned int)f2bf(fmaxf(o[4 * q + 3], 0.f)) << 16);
          int sidx = (jt * 4 + q) * 512 + cellw * 8 + hh * 4;
          *(uint2*)(A2s + sidx) = make_uint2(u0, u1);
        }
      }
    }
    __syncthreads();
    // ---- mm2: acc += A2(64x320) @ wb(320x128) for this half ----
    for (int s2 = 0; s2 < 20; ++s2) {
      short8 af = A2r[(2 * s2 + hh) * 64 + wr * 32 + m];
      short8 bf = wb8[((hf * 20 + s2) * 4 + wc) * 64 + l];
      acc = __builtin_amdgcn_mfma_f32_32x32x16_bf16(af, bf, acc, 0, 0, 0);
    }
    __syncthreads();
  }

  // ---- epilogue: C/D col=lane&31, row=(reg&3)+8*(reg>>2)+4*(lane>>5) ----
  float gb = glob[b];
  int g = wc * 32 + m;
  bool gok = g < 117;
  float br = gok ? b_reg[g] : 0.f;
  size_t rowbase = (size_t)(b * 512 + n0);
  float* cellout = out + CELL_OUT_OFF + rowbase * 117;
  float* o1out = out + OUT1_OUT_OFF + rowbase * 117;
  float spotacc = 0.f;
  #pragma unroll
  for (int reg = 0; reg < 16; ++reg) {
    int n = wr * 32 + (reg & 3) + 8 * (reg >> 2) + 4 * hh;
    float v = fmaxf(acc[reg] + br + gb, 0.f);
    spotacc += v;
    if (gok) {
      cellout[(size_t)n * 117 + g] = v;
      o1out[(size_t)n * 117 + g] = gb;
    }
  }
  float v2 = spotacc + __shfl_xor(spotacc, 32, 64);
  if (hh == 0) red[wr][wc * 32 + m] = v2;
  __syncthreads();
  if (tid < 128)
    spotp[(size_t)(b * 8 + tile) * 128 + tid] = red[0][tid] + red[1][tid];
}

// spot[b][g] = sum of 8 tile partials
__global__ __launch_bounds__(256) void spot_reduce(
    const float* __restrict__ spotp, float* __restrict__ out) {
  int idx = blockIdx.x * 256 + threadIdx.x;   // exactly 117*256 = 29952
  int b = idx / 117;
  int g = idx - b * 117;
  float s = 0.f;
  #pragma unroll
  for (int t = 0; t < 8; ++t) s += spotp[(size_t)(b * 8 + t) * 128 + g];
  out[SPOT_OUT_OFF + idx] = s;
}

extern "C" void kernel_launch(void* const* d_in, const int* in_sizes, int n_in,
                              void* d_out, int out_size, void* d_ws, size_t ws_size,
                              hipStream_t stream) {
  const float* images      = (const float*)d_in[0];
  const float* spot_images = (const float*)d_in[1];
  // d_in[2] = gene_expression (unused by the reference)
  const float* W_emph = (const float*)d_in[3];
  const float* b_emph = (const float*)d_in[4];
  const float* W_reg  = (const float*)d_in[5];
  const float* b_reg  = (const float*)d_in[6];
  const float* W_patch = (const float*)d_in[7];
  const float* b_patch = (const float*)d_in[8];
  const float* W_glob  = (const float*)d_in[9];
  const float* b_glob  = (const float*)d_in[10];
  float* out = (float*)d_out;

  unsigned short* wb   = (unsigned short*)((char*)d_ws + WB_OFF);
  unsigned short* wbig = (unsigned short*)((char*)d_ws + WBIG_OFF);
  float* glob  = (float*)((char*)d_ws + GLOB_OFF);
  float* spotp = (float*)((char*)d_ws + SPOT_OFF);

  prep_kernel<<<496, 128, 0, stream>>>(spot_images, W_patch, b_patch, W_glob,
                                       b_glob, W_reg, W_emph, b_emph, wb, wbig,
                                       glob);
  main_kernel<<<2048, 512, 0, stream>>>(images, b_reg, wb, wbig, glob, out,
                                        spotp);
  spot_reduce<<<117, 256, 0, stream>>>(spotp, out);
}